// Round 3
// baseline (422.391 us; speedup 1.0000x reference)
//
#include <hip/hip_runtime.h>
#include <stdint.h>

#define DIM 128

typedef __attribute__((ext_vector_type(8))) short short8;
typedef __attribute__((ext_vector_type(4))) float floatx4;

__device__ __forceinline__ unsigned short f2bf(float f){
  union { float f; unsigned int i; } c; c.f = f;
  unsigned int u = c.i;
  return (unsigned short)((u + 0x7fffu + ((u >> 16) & 1u)) >> 16);
}
__device__ __forceinline__ float up_lo(unsigned int v){ return __uint_as_float(v << 16); }
__device__ __forceinline__ float up_hi(unsigned int v){ return __uint_as_float(v & 0xffff0000u); }

// ---- fused f32->bf16 cast + bucket histogram (196 counters) ----------------

__global__ __launch_bounds__(256) void k_prep(const float* __restrict__ in,
    unsigned short* __restrict__ out, int n4,
    const int* __restrict__ dst, int E, int* __restrict__ bktCnt){
  __shared__ int h[256];
  h[threadIdx.x] = 0;
  __syncthreads();
  int i = blockIdx.x * 256 + threadIdx.x;
  int stride = gridDim.x * 256;
  for (int k = i; k < n4; k += stride){
    float4 v = ((const float4*)in)[k];
    ushort4 o;
    o.x = f2bf(v.x); o.y = f2bf(v.y); o.z = f2bf(v.z); o.w = f2bf(v.w);
    ((ushort4*)out)[k] = o;
  }
  for (int k = i; k < E; k += stride) atomicAdd(&h[dst[k] >> 9], 1);
  __syncthreads();
  int v = h[threadIdx.x];
  if (v) atomicAdd(&bktCnt[threadIdx.x], v);
}

// one-block exclusive scan of bucket counts; bktBase[t>=NB] = E (total)
__global__ __launch_bounds__(256) void k_scanB(const int* __restrict__ bktCnt,
    int* __restrict__ bktBase, int NB){
  __shared__ int sd[256];
  int t = threadIdx.x;
  int v = (t < NB) ? bktCnt[t] : 0;
  sd[t] = v;
  __syncthreads();
  #pragma unroll
  for (int off = 1; off < 256; off <<= 1){
    int x = (t >= off) ? sd[t - off] : 0;
    __syncthreads();
    sd[t] += x;
    __syncthreads();
  }
  bktBase[t] = sd[t] - v;   // exclusive; entries >= NB hold total E
}

// ---- legacy CSR build (fallback small-ws path) -----------------------------

__global__ __launch_bounds__(256) void k_hist(const int* __restrict__ dst, int E,
                                              int* __restrict__ deg){
  int e = blockIdx.x * 256 + threadIdx.x;
  if (e < E) atomicAdd(&deg[dst[e]], 1);
}

__global__ __launch_bounds__(256) void k_scan1(const int* __restrict__ deg, int N,
    int* __restrict__ out, int* __restrict__ bsum){
  __shared__ int sd[256];
  int t = threadIdx.x;
  int base = blockIdx.x * 1024 + t * 4;
  int v0=0, v1=0, v2=0, v3=0;
  if (base + 3 < N) { int4 q = *(const int4*)(deg + base); v0=q.x; v1=q.y; v2=q.z; v3=q.w; }
  else {
    if (base + 0 < N) v0 = deg[base + 0];
    if (base + 1 < N) v1 = deg[base + 1];
    if (base + 2 < N) v2 = deg[base + 2];
  }
  int s = v0 + v1 + v2 + v3;
  sd[t] = s;
  __syncthreads();
  #pragma unroll
  for (int off = 1; off < 256; off <<= 1){
    int x = (t >= off) ? sd[t - off] : 0;
    __syncthreads();
    sd[t] += x;
    __syncthreads();
  }
  int inc = sd[t];
  int exc = inc - s;
  if (base + 0 < N) out[base + 0] = exc;
  if (base + 1 < N) out[base + 1] = exc + v0;
  if (base + 2 < N) out[base + 2] = exc + v0 + v1;
  if (base + 3 < N) out[base + 3] = exc + v0 + v1 + v2;
  if (t == 255) bsum[blockIdx.x] = inc;
}

__global__ __launch_bounds__(128) void k_scan2(int* __restrict__ bsum, int nb){
  __shared__ int sd[128];
  int t = threadIdx.x;
  int v = (t < nb) ? bsum[t] : 0;
  sd[t] = v;
  __syncthreads();
  #pragma unroll
  for (int off = 1; off < 128; off <<= 1){
    int x = (t >= off) ? sd[t - off] : 0;
    __syncthreads();
    sd[t] += x;
    __syncthreads();
  }
  if (t < nb) bsum[t] = sd[t] - v;
}

__global__ __launch_bounds__(256) void k_scan3(int* __restrict__ rowptr,
    const int* __restrict__ bsum, int N, int E, int* __restrict__ cursor){
  int i = blockIdx.x * 256 + threadIdx.x;
  if (i < N){
    int v = rowptr[i] + bsum[i >> 10];
    rowptr[i] = v;
    cursor[i] = v;
  }
  if (i == 0) rowptr[N] = E;
}

__global__ __launch_bounds__(256) void k_fill(const int* __restrict__ src,
    const int* __restrict__ dst, int E, int* __restrict__ cursor, int* __restrict__ col){
  int e = blockIdx.x * 256 + threadIdx.x;
  if (e < E){
    int d = dst[e];
    int pos = atomicAdd(&cursor[d], 1);
    col[pos] = src[e];
  }
}

// ---- bucketed CSR fill, pass A: bin (src,dst) by dst>>9 --------------------

__global__ __launch_bounds__(256) void k_bin(const int* __restrict__ src,
    const int* __restrict__ dst, int E,
    const int* __restrict__ bucketBase, int* __restrict__ cursor,
    int2* __restrict__ binned, int NB){
  __shared__ int2 buf[4096];
  __shared__ unsigned char bidArr[4096];
  __shared__ int cnt[256], startA[256], gstart[256], gbase[256];
  int t = threadIdx.x;
  cnt[t] = 0;
  if (t < NB) gbase[t] = bucketBase[t];
  __syncthreads();
  int base = blockIdx.x * 4096;
  int s_[16], d_[16], r_[16];
  #pragma unroll
  for (int i = 0; i < 16; ++i){
    int e = base + i * 256 + t;
    bool v = (e < E);
    s_[i] = v ? src[e] : 0;
    d_[i] = v ? dst[e] : -1;
    r_[i] = v ? atomicAdd(&cnt[d_[i] >> 9], 1) : 0;
  }
  __syncthreads();
  int v = cnt[t];
  startA[t] = v;
  __syncthreads();
  #pragma unroll
  for (int off = 1; off < 256; off <<= 1){
    int y = (t >= off) ? startA[t - off] : 0;
    __syncthreads();
    startA[t] += y;
    __syncthreads();
  }
  int incl = startA[t];
  __syncthreads();
  startA[t] = incl - v;
  __syncthreads();
  #pragma unroll
  for (int i = 0; i < 16; ++i){
    if (d_[i] >= 0){
      int b = d_[i] >> 9;
      int slot = startA[b] + r_[i];
      buf[slot] = make_int2(s_[i], d_[i]);
      bidArr[slot] = (unsigned char)b;
    }
  }
  if (cnt[t] > 0) gstart[t] = atomicAdd(&cursor[t], cnt[t]);
  __syncthreads();
  int total = startA[255] + cnt[255];
  for (int j = t; j < total; j += 256){
    int b = bidArr[j];
    binned[gbase[b] + gstart[b] + (j - startA[b])] = buf[j];
  }
}

// ---- bucketed CSR fill, pass B: local degrees + scan + rowptr + scatter ----

__global__ __launch_bounds__(256) void k_csr2(const int2* __restrict__ binned,
    const int* __restrict__ bktBase, int N, int* __restrict__ rowptr,
    int* __restrict__ col){
  __shared__ int cnt[512], excl[512], cur[512];
  __shared__ int sd[256];
  int b = blockIdx.x;
  int node0 = b << 9;
  int nNodes = min(512, N - node0);
  int t = threadIdx.x;
  cnt[t] = 0; cnt[t + 256] = 0;
  __syncthreads();
  int lo = bktBase[b], hi = bktBase[b + 1];
  for (int e = lo + t; e < hi; e += 256)
    atomicAdd(&cnt[binned[e].y - node0], 1);
  __syncthreads();
  int c0 = cnt[2 * t], c1 = cnt[2 * t + 1];
  int ps = c0 + c1;
  sd[t] = ps;
  __syncthreads();
  #pragma unroll
  for (int off = 1; off < 256; off <<= 1){
    int x = (t >= off) ? sd[t - off] : 0;
    __syncthreads();
    sd[t] += x;
    __syncthreads();
  }
  int pexcl = sd[t] - ps;
  excl[2 * t] = pexcl;
  excl[2 * t + 1] = pexcl + c0;
  cur[2 * t] = 0; cur[2 * t + 1] = 0;
  __syncthreads();
  for (int j = t; j < nNodes; j += 256) rowptr[node0 + j] = lo + excl[j];
  if (t == 0) rowptr[node0 + nNodes] = hi;  // dup of next bucket's base: same value
  for (int e = lo + t; e < hi; e += 256){
    int2 pr = binned[e];
    int dl = pr.y - node0;
    int loc = atomicAdd(&cur[dl], 1);
    col[lo + excl[dl] + loc] = pr.x;
  }
}

// ---- bf16 mean aggregation: wave-per-node, scalar-base row loads -----------
// Lane owns 2 elements; 64 lanes x 4B = one full 256B row per load.
// Neighbor indices are made wave-uniform via readlane -> feat row base is an
// SGPR pair -> global_load_dword with SGPR base + lane offset: near-zero VALU
// address math, no cross-lane reduce, no divergent epilogue. 16 loads are
// issued back-to-back before any accumulate waits on them.

__global__ __launch_bounds__(256) void k_agg_bf(const unsigned short* __restrict__ feat,
    const int* __restrict__ rowptr, const int* __restrict__ col,
    unsigned short* __restrict__ out, int N){
  int wid = (blockIdx.x * 256 + threadIdx.x) >> 6;
  if (wid >= N) return;
  int lane = threadIdx.x & 63;
  int beg = __builtin_amdgcn_readfirstlane(rowptr[wid]);
  int end = __builtin_amdgcn_readfirstlane(rowptr[wid + 1]);
  int deg = end - beg;
  float a0 = 0.f, a1 = 0.f;
  int ls = lane & 15;

  for (int e = beg; e < end; e += 16){
    int cnt = end - e; cnt = cnt > 16 ? 16 : cnt;
    int idx = col[e + (ls < cnt ? ls : 0)];
    unsigned int u[16];
    // issue all loads first (no waitcnt between them)
    #pragma unroll
    for (int j = 0; j < 16; ++j){
      if (j < cnt){
        int n = __builtin_amdgcn_readlane(idx, j);
        u[j] = *(const unsigned int*)(feat + (size_t)n * DIM + (lane << 1));
      }
    }
    // then accumulate
    #pragma unroll
    for (int j = 0; j < 16; ++j){
      if (j < cnt){ a0 += up_lo(u[j]); a1 += up_hi(u[j]); }
    }
  }

  float r = 1.0f / (float)(deg > 1 ? deg : 1);
  unsigned int o = (unsigned int)f2bf(a0 * r) | ((unsigned int)f2bf(a1 * r) << 16);
  *(unsigned int*)(out + (size_t)wid * DIM + (lane << 1)) = o;
}

// ---- f32 mean aggregation (fallback small-ws path) -------------------------

__global__ __launch_bounds__(256) void k_agg_f32(const float* __restrict__ feat,
    const int* __restrict__ rowptr, const int* __restrict__ col,
    unsigned short* __restrict__ out, int N){
  int wid = (blockIdx.x * 256 + threadIdx.x) >> 6;
  if (wid >= N) return;
  int lane = threadIdx.x & 63;
  int beg = rowptr[wid], end = rowptr[wid + 1];
  float a0 = 0.f, a1 = 0.f;
  int off = lane * 2;
  int e = beg;
  for (; e + 4 <= end; e += 4){
    int s0 = col[e], s1 = col[e+1], s2 = col[e+2], s3 = col[e+3];
    float2 v0 = *(const float2*)(feat + (size_t)s0 * DIM + off);
    float2 v1 = *(const float2*)(feat + (size_t)s1 * DIM + off);
    float2 v2 = *(const float2*)(feat + (size_t)s2 * DIM + off);
    float2 v3 = *(const float2*)(feat + (size_t)s3 * DIM + off);
    a0 += v0.x + v1.x + v2.x + v3.x;
    a1 += v0.y + v1.y + v2.y + v3.y;
  }
  for (; e < end; ++e){
    float2 v = *(const float2*)(feat + (size_t)col[e] * DIM + off);
    a0 += v.x; a1 += v.y;
  }
  int d = end - beg;
  float r = 1.0f / (float)(d > 1 ? d : 1);
  a0 *= r; a1 *= r;
  unsigned int o = (unsigned int)f2bf(a0) | ((unsigned int)f2bf(a1) << 16);
  *(unsigned int*)(out + (size_t)wid * DIM + off) = o;
}

// ---- B-stationary register GEMM: out = relu(A1@Wl + A2@Wr + bias) ----------

template<bool OUTBF>
__global__ __launch_bounds__(256) void k_gemm_r(const unsigned short* __restrict__ A1,
    const unsigned short* __restrict__ A2,
    const float* __restrict__ Wl, const float* __restrict__ Wr,
    const float* __restrict__ bias,
    float* __restrict__ outf, unsigned short* __restrict__ outb, int M)
{
  int lane = threadIdx.x & 63;
  int c = lane & 15, quad = lane >> 4;
  int gwid = blockIdx.x * 4 + (threadIdx.x >> 6);
  int nwaves = gridDim.x * 4;
  int half = gwid & 1;
  int colbase = half * 64;

  short8 B[2][4][4];
  #pragma unroll
  for (int w = 0; w < 2; ++w){
    const float* W = w ? Wr : Wl;
    #pragma unroll
    for (int km = 0; km < 4; ++km){
      #pragma unroll
      for (int j = 0; j < 4; ++j){
        union { short8 v; unsigned short u[8]; } tb;
        #pragma unroll
        for (int i = 0; i < 8; ++i)
          tb.u[i] = f2bf(W[(km * 32 + quad * 8 + i) * 128 + colbase + j * 16 + c]);
        B[w][km][j] = tb.v;
      }
    }
  }
  float bv[4];
  #pragma unroll
  for (int j = 0; j < 4; ++j) bv[j] = bias[colbase + j * 16 + c];

  int ntasks = M >> 4;
  for (int task = gwid >> 1; task < ntasks; task += nwaves >> 1){
    int row0 = task << 4;
    const unsigned short* ap1 = A1 + (size_t)(row0 + c) * DIM + quad * 8;
    const unsigned short* ap2 = A2 + (size_t)(row0 + c) * DIM + quad * 8;
    short8 a1[4], a2[4];
    #pragma unroll
    for (int km = 0; km < 4; ++km){
      a1[km] = *(const short8*)(ap1 + km * 32);
      a2[km] = *(const short8*)(ap2 + km * 32);
    }
    floatx4 acc[4];
    #pragma unroll
    for (int j = 0; j < 4; ++j) acc[j] = (floatx4){0.f, 0.f, 0.f, 0.f};
    #pragma unroll
    for (int km = 0; km < 4; ++km){
      #pragma unroll
      for (int j = 0; j < 4; ++j){
        acc[j] = __builtin_amdgcn_mfma_f32_16x16x32_bf16(a1[km], B[0][km][j], acc[j], 0, 0, 0);
        acc[j] = __builtin_amdgcn_mfma_f32_16x16x32_bf16(a2[km], B[1][km][j], acc[j], 0, 0, 0);
      }
    }
    #pragma unroll
    for (int j = 0; j < 4; ++j){
      int colIdx = colbase + j * 16 + c;
      #pragma unroll
      for (int r = 0; r < 4; ++r){
        int row = row0 + quad * 4 + r;
        float v = fmaxf(acc[j][r] + bv[j], 0.f);
        if (OUTBF) outb[(size_t)row * DIM + colIdx] = f2bf(v);
        else       outf[(size_t)row * DIM + colIdx] = v;
      }
    }
  }
}

// ---- fallback LDS GEMM (small-ws path, f32 A2/out) -------------------------

__global__ __launch_bounds__(256) void k_gemm_f(const unsigned short* __restrict__ A1,
    const float* __restrict__ A2f,
    const float* __restrict__ Wl, const float* __restrict__ Wr,
    const float* __restrict__ bias, float* __restrict__ outf, int M)
{
  __shared__ unsigned short lds[2 * 128 * 128];
  for (int h = threadIdx.x; h < 128 * 128; h += 256){
    int k = h >> 7, n = h & 127;
    int idx = n * 128 + ((((k >> 3) ^ (n & 7)) << 3)) + (k & 7);
    lds[idx]         = f2bf(Wl[h]);
    lds[16384 + idx] = f2bf(Wr[h]);
  }
  __syncthreads();
  int lane = threadIdx.x & 63;
  int c = lane & 15, quad = lane >> 4;
  int gwid = blockIdx.x * 4 + (threadIdx.x >> 6);
  int nwaves = gridDim.x * 4;
  int ntasks = M >> 4;
  for (int task = gwid; task < ntasks; task += nwaves){
    int row0 = task << 4;
    floatx4 acc[8];
    #pragma unroll
    for (int j = 0; j < 8; ++j) acc[j] = (floatx4){0.f, 0.f, 0.f, 0.f};
    const unsigned short* ap1 = A1 + (size_t)(row0 + c) * DIM + quad * 8;
    #pragma unroll
    for (int km = 0; km < 4; ++km){
      short8 a = *(const short8*)(ap1 + km * 32);
      int kb = (km << 2) + quad;
      #pragma unroll
      for (int j = 0; j < 8; ++j){
        short8 b = *(const short8*)(&lds[(j * 16 + c) * 128 + ((kb ^ (c & 7)) << 3)]);
        acc[j] = __builtin_amdgcn_mfma_f32_16x16x32_bf16(a, b, acc[j], 0, 0, 0);
      }
    }
    #pragma unroll
    for (int km = 0; km < 4; ++km){
      const float* ap2 = A2f + (size_t)(row0 + c) * DIM + quad * 8;
      float4 p0 = *(const float4*)(ap2 + km * 32);
      float4 p1 = *(const float4*)(ap2 + km * 32 + 4);
      union { short8 v; unsigned short u[8]; } ua;
      ua.u[0] = f2bf(p0.x); ua.u[1] = f2bf(p0.y);
      ua.u[2] = f2bf(p0.z); ua.u[3] = f2bf(p0.w);
      ua.u[4] = f2bf(p1.x); ua.u[5] = f2bf(p1.y);
      ua.u[6] = f2bf(p1.z); ua.u[7] = f2bf(p1.w);
      int kb = (km << 2) + quad;
      #pragma unroll
      for (int j = 0; j < 8; ++j){
        short8 b = *(const short8*)(&lds[16384 + (j * 16 + c) * 128 + ((kb ^ (c & 7)) << 3)]);
        acc[j] = __builtin_amdgcn_mfma_f32_16x16x32_bf16(ua.v, b, acc[j], 0, 0, 0);
      }
    }
    #pragma unroll
    for (int j = 0; j < 8; ++j){
      int colIdx = j * 16 + c;
      float bvv = bias[colIdx];
      #pragma unroll
      for (int r = 0; r < 4; ++r){
        int row = row0 + quad * 4 + r;
        outf[(size_t)row * DIM + colIdx] = fmaxf(acc[j][r] + bvv, 0.f);
      }
    }
  }
}

// ---- host ------------------------------------------------------------------

extern "C" void kernel_launch(void* const* d_in, const int* in_sizes, int n_in,
                              void* d_out, int out_size, void* d_ws, size_t ws_size,
                              hipStream_t stream)
{
  const float* x   = (const float*)d_in[0];
  const int*   ei  = (const int*)d_in[1];
  const float* Wl1 = (const float*)d_in[2];
  const float* bl1 = (const float*)d_in[3];
  const float* Wr1 = (const float*)d_in[4];
  const float* Wl2 = (const float*)d_in[5];
  const float* bl2 = (const float*)d_in[6];
  const float* Wr2 = (const float*)d_in[7];

  const int N = in_sizes[0] / DIM;
  const int E = in_sizes[1] / 2;
  const int* src  = ei;
  const int* dstI = ei + E;
  const int NB = (N + 511) >> 9;   // 196 (must be <= 255 for k_bin's uchar)

  char* p = (char*)d_ws;
  auto alloc = [&](size_t bytes) -> char* {
    char* r = p; p += (bytes + 255) & ~((size_t)255); return r;
  };
  int* rowptr   = (int*)alloc((size_t)(N + 1) * 4);
  int* deg      = (int*)alloc((size_t)N * 4);   // fallback only
  int* bsum     = (int*)alloc(1024);            // fallback only
  int* bktCnt   = (int*)alloc(1024);
  int* bktCur   = (int*)alloc(1024);            // adjacent to bktCnt: one memset
  int* bktBase  = (int*)alloc(2048);            // 257 entries used
  int* col      = (int*)alloc((size_t)E * 4);
  unsigned short* aggb = (unsigned short*)alloc((size_t)N * DIM * 2);
  unsigned short* xb   = (unsigned short*)alloc((size_t)N * DIM * 2);
  unsigned short* h1b  = (unsigned short*)alloc((size_t)N * DIM * 2);
  size_t need_big = (size_t)(p - (char*)d_ws);
  const bool big = (ws_size >= need_big) && (NB <= 255);
  int2* binned = (int2*)aggb;   // overlays aggb (dead until first k_agg write)

  int gE = (E + 255) / 256;
  int gAgg = (N * 64 + 255) / 256;

  if (big){
    int n4 = N * DIM / 4;
    hipMemsetAsync(bktCnt, 0, 2048, stream);   // bktCnt + bktCur
    k_prep<<<1024, 256, 0, stream>>>(x, xb, n4, dstI, E, bktCnt);
    k_scanB<<<1, 256, 0, stream>>>(bktCnt, bktBase, NB);
    k_bin<<<(E + 4095) / 4096, 256, 0, stream>>>(src, dstI, E, bktBase, bktCur,
                                                 binned, NB);
    k_csr2<<<NB, 256, 0, stream>>>(binned, bktBase, N, rowptr, col);
    k_agg_bf<<<gAgg, 256, 0, stream>>>(xb, rowptr, col, aggb, N);
    k_gemm_r<true><<<512, 256, 0, stream>>>(aggb, xb, Wl1, Wr1, bl1,
                                            nullptr, h1b, N);
    k_agg_bf<<<gAgg, 256, 0, stream>>>(h1b, rowptr, col, aggb, N);
    k_gemm_r<false><<<512, 256, 0, stream>>>(aggb, h1b, Wl2, Wr2, bl2,
                                             (float*)d_out, nullptr, N);
  } else {
    hipMemsetAsync(deg, 0, (size_t)N * 4, stream);
    k_hist<<<gE, 256, 0, stream>>>(dstI, E, deg);
    int nb = (N + 1023) / 1024;
    k_scan1<<<nb, 256, 0, stream>>>(deg, N, rowptr, bsum);
    k_scan2<<<1, 128, 0, stream>>>(bsum, nb);
    k_scan3<<<(N + 255) / 256, 256, 0, stream>>>(rowptr, bsum, N, E, /*cursor=*/deg);
    k_fill<<<gE, 256, 0, stream>>>(src, dstI, E, /*cursor=*/deg, col);
    float* h1 = (float*)d_out;
    k_agg_f32<<<gAgg, 256, 0, stream>>>(x, rowptr, col, aggb, N);
    k_gemm_f<<<512, 256, 0, stream>>>(aggb, x, Wl1, Wr1, bl1, h1, N);
    k_agg_f32<<<gAgg, 256, 0, stream>>>(h1, rowptr, col, aggb, N);
    k_gemm_f<<<512, 256, 0, stream>>>(aggb, h1, Wl2, Wr2, bl2, (float*)d_out, N);
  }
}

// Round 4
// 329.390 us; speedup vs baseline: 1.2823x; 1.2823x over previous
//
#include <hip/hip_runtime.h>
#include <stdint.h>

#define DIM 128

typedef __attribute__((ext_vector_type(8))) short short8;
typedef __attribute__((ext_vector_type(4))) float floatx4;

__device__ __forceinline__ unsigned short f2bf(float f){
  union { float f; unsigned int i; } c; c.f = f;
  unsigned int u = c.i;
  return (unsigned short)((u + 0x7fffu + ((u >> 16) & 1u)) >> 16);
}
__device__ __forceinline__ float up_lo(unsigned int v){ return __uint_as_float(v << 16); }
__device__ __forceinline__ float up_hi(unsigned int v){ return __uint_as_float(v & 0xffff0000u); }

// ---- fused f32->bf16 cast + bucket histogram (196 counters) ----------------

__global__ __launch_bounds__(256) void k_prep(const float* __restrict__ in,
    unsigned short* __restrict__ out, int n4,
    const int* __restrict__ dst, int E, int* __restrict__ bktCnt){
  __shared__ int h[256];
  h[threadIdx.x] = 0;
  __syncthreads();
  int i = blockIdx.x * 256 + threadIdx.x;
  int stride = gridDim.x * 256;
  for (int k = i; k < n4; k += stride){
    float4 v = ((const float4*)in)[k];
    ushort4 o;
    o.x = f2bf(v.x); o.y = f2bf(v.y); o.z = f2bf(v.z); o.w = f2bf(v.w);
    ((ushort4*)out)[k] = o;
  }
  for (int k = i; k < E; k += stride) atomicAdd(&h[dst[k] >> 9], 1);
  __syncthreads();
  int v = h[threadIdx.x];
  if (v) atomicAdd(&bktCnt[threadIdx.x], v);
}

// one-block exclusive scan of bucket counts; bktBase[t>=NB] = E (total)
__global__ __launch_bounds__(256) void k_scanB(const int* __restrict__ bktCnt,
    int* __restrict__ bktBase, int NB){
  __shared__ int sd[256];
  int t = threadIdx.x;
  int v = (t < NB) ? bktCnt[t] : 0;
  sd[t] = v;
  __syncthreads();
  #pragma unroll
  for (int off = 1; off < 256; off <<= 1){
    int x = (t >= off) ? sd[t - off] : 0;
    __syncthreads();
    sd[t] += x;
    __syncthreads();
  }
  bktBase[t] = sd[t] - v;   // exclusive; entries >= NB hold total E
}

// ---- legacy CSR build (fallback small-ws path) -----------------------------

__global__ __launch_bounds__(256) void k_hist(const int* __restrict__ dst, int E,
                                              int* __restrict__ deg){
  int e = blockIdx.x * 256 + threadIdx.x;
  if (e < E) atomicAdd(&deg[dst[e]], 1);
}

__global__ __launch_bounds__(256) void k_scan1(const int* __restrict__ deg, int N,
    int* __restrict__ out, int* __restrict__ bsum){
  __shared__ int sd[256];
  int t = threadIdx.x;
  int base = blockIdx.x * 1024 + t * 4;
  int v0=0, v1=0, v2=0, v3=0;
  if (base + 3 < N) { int4 q = *(const int4*)(deg + base); v0=q.x; v1=q.y; v2=q.z; v3=q.w; }
  else {
    if (base + 0 < N) v0 = deg[base + 0];
    if (base + 1 < N) v1 = deg[base + 1];
    if (base + 2 < N) v2 = deg[base + 2];
  }
  int s = v0 + v1 + v2 + v3;
  sd[t] = s;
  __syncthreads();
  #pragma unroll
  for (int off = 1; off < 256; off <<= 1){
    int x = (t >= off) ? sd[t - off] : 0;
    __syncthreads();
    sd[t] += x;
    __syncthreads();
  }
  int inc = sd[t];
  int exc = inc - s;
  if (base + 0 < N) out[base + 0] = exc;
  if (base + 1 < N) out[base + 1] = exc + v0;
  if (base + 2 < N) out[base + 2] = exc + v0 + v1;
  if (base + 3 < N) out[base + 3] = exc + v0 + v1 + v2;
  if (t == 255) bsum[blockIdx.x] = inc;
}

__global__ __launch_bounds__(128) void k_scan2(int* __restrict__ bsum, int nb){
  __shared__ int sd[128];
  int t = threadIdx.x;
  int v = (t < nb) ? bsum[t] : 0;
  sd[t] = v;
  __syncthreads();
  #pragma unroll
  for (int off = 1; off < 128; off <<= 1){
    int x = (t >= off) ? sd[t - off] : 0;
    __syncthreads();
    sd[t] += x;
    __syncthreads();
  }
  if (t < nb) bsum[t] = sd[t] - v;
}

__global__ __launch_bounds__(256) void k_scan3(int* __restrict__ rowptr,
    const int* __restrict__ bsum, int N, int E, int* __restrict__ cursor){
  int i = blockIdx.x * 256 + threadIdx.x;
  if (i < N){
    int v = rowptr[i] + bsum[i >> 10];
    rowptr[i] = v;
    cursor[i] = v;
  }
  if (i == 0) rowptr[N] = E;
}

__global__ __launch_bounds__(256) void k_fill(const int* __restrict__ src,
    const int* __restrict__ dst, int E, int* __restrict__ cursor, int* __restrict__ col){
  int e = blockIdx.x * 256 + threadIdx.x;
  if (e < E){
    int d = dst[e];
    int pos = atomicAdd(&cursor[d], 1);
    col[pos] = src[e];
  }
}

// ---- bucketed CSR fill, pass A: bin (src,dst) by dst>>9 --------------------
// 2048-edge chunks: 782 blocks (~3/CU resident) for latency hiding.

#define BINCH 2048

__global__ __launch_bounds__(256) void k_bin(const int* __restrict__ src,
    const int* __restrict__ dst, int E,
    const int* __restrict__ bucketBase, int* __restrict__ cursor,
    int2* __restrict__ binned, int NB){
  __shared__ int2 buf[BINCH];
  __shared__ unsigned char bidArr[BINCH];
  __shared__ int cnt[256], startA[256], gstart[256], gbase[256];
  int t = threadIdx.x;
  cnt[t] = 0;
  if (t < NB) gbase[t] = bucketBase[t];
  __syncthreads();
  int base = blockIdx.x * BINCH;
  int s_[8], d_[8], r_[8];
  #pragma unroll
  for (int i = 0; i < 8; ++i){
    int e = base + i * 256 + t;
    bool v = (e < E);
    s_[i] = v ? src[e] : 0;
    d_[i] = v ? dst[e] : -1;
    r_[i] = v ? atomicAdd(&cnt[d_[i] >> 9], 1) : 0;
  }
  __syncthreads();
  int v = cnt[t];
  startA[t] = v;
  __syncthreads();
  #pragma unroll
  for (int off = 1; off < 256; off <<= 1){
    int y = (t >= off) ? startA[t - off] : 0;
    __syncthreads();
    startA[t] += y;
    __syncthreads();
  }
  int incl = startA[t];
  __syncthreads();
  startA[t] = incl - v;
  __syncthreads();
  #pragma unroll
  for (int i = 0; i < 8; ++i){
    if (d_[i] >= 0){
      int b = d_[i] >> 9;
      int slot = startA[b] + r_[i];
      buf[slot] = make_int2(s_[i], d_[i]);
      bidArr[slot] = (unsigned char)b;
    }
  }
  if (cnt[t] > 0) gstart[t] = atomicAdd(&cursor[t], cnt[t]);
  __syncthreads();
  int total = startA[255] + cnt[255];
  for (int j = t; j < total; j += 256){
    int b = bidArr[j];
    binned[gbase[b] + gstart[b] + (j - startA[b])] = buf[j];
  }
}

// ---- bucketed CSR fill, pass B: local degrees + scan + rowptr + scatter ----
// 1024 threads/block: 8 serial iterations per pass instead of 32 (one block
// per bucket is fixed at NB=196, so per-block depth is the parallelism lever).

__global__ __launch_bounds__(1024) void k_csr2(const int2* __restrict__ binned,
    const int* __restrict__ bktBase, int N, int* __restrict__ rowptr,
    int* __restrict__ col){
  __shared__ int cnt[512], excl[512], cur[512];
  __shared__ int sd[256];
  int b = blockIdx.x;
  int node0 = b << 9;
  int nNodes = min(512, N - node0);
  int t = threadIdx.x;
  if (t < 512){ cnt[t] = 0; cur[t] = 0; }
  __syncthreads();
  int lo = bktBase[b], hi = bktBase[b + 1];
  for (int e = lo + t; e < hi; e += 1024)
    atomicAdd(&cnt[binned[e].y - node0], 1);
  __syncthreads();
  int c0 = 0, c1 = 0, ps = 0;
  if (t < 256){
    c0 = cnt[2 * t]; c1 = cnt[2 * t + 1];
    ps = c0 + c1;
    sd[t] = ps;
  }
  __syncthreads();
  #pragma unroll
  for (int off = 1; off < 256; off <<= 1){
    int x = 0;
    if (t < 256 && t >= off) x = sd[t - off];
    __syncthreads();
    if (t < 256) sd[t] += x;
    __syncthreads();
  }
  if (t < 256){
    int pexcl = sd[t] - ps;
    excl[2 * t] = pexcl;
    excl[2 * t + 1] = pexcl + c0;
  }
  __syncthreads();
  for (int j = t; j < nNodes; j += 1024) rowptr[node0 + j] = lo + excl[j];
  if (t == 0) rowptr[node0 + nNodes] = hi;  // dup of next bucket's base: same value
  for (int e = lo + t; e < hi; e += 1024){
    int2 pr = binned[e];
    int dl = pr.y - node0;
    int loc = atomicAdd(&cur[dl], 1);
    col[lo + excl[dl] + loc] = pr.x;
  }
}

// ---- bf16 mean aggregation: quarter-wave row gathers (round-1 proven) ------
// One coalesced wave-wide col load covers the first 64 neighbor indices;
// indices distributed in-register via shfl so up to 8 row loads (16B/lane,
// 1KB/wave each) are in flight with no per-iteration col->row chain.

__device__ __forceinline__ void acc8(float* a, uint4 u){
  a[0] += up_lo(u.x); a[1] += up_hi(u.x);
  a[2] += up_lo(u.y); a[3] += up_hi(u.y);
  a[4] += up_lo(u.z); a[5] += up_hi(u.z);
  a[6] += up_lo(u.w); a[7] += up_hi(u.w);
}

__global__ __launch_bounds__(256) void k_agg_bf(const unsigned short* __restrict__ feat,
    const int* __restrict__ rowptr, const int* __restrict__ col,
    unsigned short* __restrict__ out, int N){
  int wid = (blockIdx.x * 256 + threadIdx.x) >> 6;
  if (wid >= N) return;
  int lane = threadIdx.x & 63;
  int q = lane >> 4, s = lane & 15;
  int beg = rowptr[wid], end = rowptr[wid + 1];
  int deg = end - beg;
  float a[8];
  #pragma unroll
  for (int i = 0; i < 8; ++i) a[i] = 0.f;

  // one coalesced 256B load of (up to) the first 64 neighbor indices
  int myIdx = (beg + lane < end) ? col[beg + lane] : 0;

  // group 0: edge offsets q, 4+q, 8+q, 12+q
  int o0 = q, o1 = 4 + q, o2 = 8 + q, o3 = 12 + q;
  int n0 = __shfl(myIdx, o0, 64);
  int n1 = __shfl(myIdx, o1, 64);
  int n2 = __shfl(myIdx, o2, 64);
  int n3 = __shfl(myIdx, o3, 64);
  uint4 u0 = ((const uint4*)(feat + (size_t)n0 * DIM))[s];
  uint4 u1 = ((const uint4*)(feat + (size_t)n1 * DIM))[s];
  uint4 u2 = ((const uint4*)(feat + (size_t)n2 * DIM))[s];
  uint4 u3 = ((const uint4*)(feat + (size_t)n3 * DIM))[s];

  bool g1 = deg > 16;
  int o4 = 16 + q, o5 = 20 + q, o6 = 24 + q, o7 = 28 + q;
  uint4 u4, u5, u6, u7;
  if (g1){
    int n4 = __shfl(myIdx, o4, 64);
    int n5 = __shfl(myIdx, o5, 64);
    int n6 = __shfl(myIdx, o6, 64);
    int n7 = __shfl(myIdx, o7, 64);
    u4 = ((const uint4*)(feat + (size_t)n4 * DIM))[s];
    u5 = ((const uint4*)(feat + (size_t)n5 * DIM))[s];
    u6 = ((const uint4*)(feat + (size_t)n6 * DIM))[s];
    u7 = ((const uint4*)(feat + (size_t)n7 * DIM))[s];
  }

  if (o0 < deg) acc8(a, u0);
  if (o1 < deg) acc8(a, u1);
  if (o2 < deg) acc8(a, u2);
  if (o3 < deg) acc8(a, u3);
  if (g1){
    if (o4 < deg) acc8(a, u4);
    if (o5 < deg) acc8(a, u5);
    if (o6 < deg) acc8(a, u6);
    if (o7 < deg) acc8(a, u7);
  }

  // rare path: degree > 32 (Poisson(16) tail), generic predicated 16-edge loop
  for (int e = beg + 32; e < end; e += 16){
    int i0 = e + q, i1 = e + 4 + q, i2 = e + 8 + q, i3 = e + 12 + q;
    int m0 = col[i0 < end ? i0 : beg];
    int m1 = col[i1 < end ? i1 : beg];
    int m2 = col[i2 < end ? i2 : beg];
    int m3 = col[i3 < end ? i3 : beg];
    uint4 v0 = ((const uint4*)(feat + (size_t)m0 * DIM))[s];
    uint4 v1 = ((const uint4*)(feat + (size_t)m1 * DIM))[s];
    uint4 v2 = ((const uint4*)(feat + (size_t)m2 * DIM))[s];
    uint4 v3 = ((const uint4*)(feat + (size_t)m3 * DIM))[s];
    if (i0 < end) acc8(a, v0);
    if (i1 < end) acc8(a, v1);
    if (i2 < end) acc8(a, v2);
    if (i3 < end) acc8(a, v3);
  }

  #pragma unroll
  for (int i = 0; i < 8; ++i){
    a[i] += __shfl_xor(a[i], 16, 64);
    a[i] += __shfl_xor(a[i], 32, 64);
  }
  if (q == 0){
    int d = deg;
    float r = 1.0f / (float)(d > 1 ? d : 1);
    uint4 o;
    o.x = (unsigned int)f2bf(a[0] * r) | ((unsigned int)f2bf(a[1] * r) << 16);
    o.y = (unsigned int)f2bf(a[2] * r) | ((unsigned int)f2bf(a[3] * r) << 16);
    o.z = (unsigned int)f2bf(a[4] * r) | ((unsigned int)f2bf(a[5] * r) << 16);
    o.w = (unsigned int)f2bf(a[6] * r) | ((unsigned int)f2bf(a[7] * r) << 16);
    ((uint4*)(out + (size_t)wid * DIM))[s] = o;
  }
}

// ---- f32 mean aggregation (fallback small-ws path) -------------------------

__global__ __launch_bounds__(256) void k_agg_f32(const float* __restrict__ feat,
    const int* __restrict__ rowptr, const int* __restrict__ col,
    unsigned short* __restrict__ out, int N){
  int wid = (blockIdx.x * 256 + threadIdx.x) >> 6;
  if (wid >= N) return;
  int lane = threadIdx.x & 63;
  int beg = rowptr[wid], end = rowptr[wid + 1];
  float a0 = 0.f, a1 = 0.f;
  int off = lane * 2;
  int e = beg;
  for (; e + 4 <= end; e += 4){
    int s0 = col[e], s1 = col[e+1], s2 = col[e+2], s3 = col[e+3];
    float2 v0 = *(const float2*)(feat + (size_t)s0 * DIM + off);
    float2 v1 = *(const float2*)(feat + (size_t)s1 * DIM + off);
    float2 v2 = *(const float2*)(feat + (size_t)s2 * DIM + off);
    float2 v3 = *(const float2*)(feat + (size_t)s3 * DIM + off);
    a0 += v0.x + v1.x + v2.x + v3.x;
    a1 += v0.y + v1.y + v2.y + v3.y;
  }
  for (; e < end; ++e){
    float2 v = *(const float2*)(feat + (size_t)col[e] * DIM + off);
    a0 += v.x; a1 += v.y;
  }
  int d = end - beg;
  float r = 1.0f / (float)(d > 1 ? d : 1);
  a0 *= r; a1 *= r;
  unsigned int o = (unsigned int)f2bf(a0) | ((unsigned int)f2bf(a1) << 16);
  *(unsigned int*)(out + (size_t)wid * DIM + off) = o;
}

// ---- B-stationary register GEMM with A-prefetch ----------------------------
// out = relu(A1@Wl + A2@Wr + bias); next task's A fragments are loaded before
// the current task's MFMAs so load latency hides behind compute.

template<bool OUTBF>
__global__ __launch_bounds__(256, 2) void k_gemm_r(const unsigned short* __restrict__ A1,
    const unsigned short* __restrict__ A2,
    const float* __restrict__ Wl, const float* __restrict__ Wr,
    const float* __restrict__ bias,
    float* __restrict__ outf, unsigned short* __restrict__ outb, int M)
{
  int lane = threadIdx.x & 63;
  int c = lane & 15, quad = lane >> 4;
  int gwid = blockIdx.x * 4 + (threadIdx.x >> 6);
  int nwaves = gridDim.x * 4;
  int half = gwid & 1;
  int colbase = half * 64;

  short8 B[2][4][4];
  #pragma unroll
  for (int w = 0; w < 2; ++w){
    const float* W = w ? Wr : Wl;
    #pragma unroll
    for (int km = 0; km < 4; ++km){
      #pragma unroll
      for (int j = 0; j < 4; ++j){
        union { short8 v; unsigned short u[8]; } tb;
        #pragma unroll
        for (int i = 0; i < 8; ++i)
          tb.u[i] = f2bf(W[(km * 32 + quad * 8 + i) * 128 + colbase + j * 16 + c]);
        B[w][km][j] = tb.v;
      }
    }
  }
  float bv[4];
  #pragma unroll
  for (int j = 0; j < 4; ++j) bv[j] = bias[colbase + j * 16 + c];

  int ntasks = M >> 4;
  int stride = nwaves >> 1;
  int task = gwid >> 1;
  short8 a1[4], a2[4];
  if (task < ntasks){
    const unsigned short* ap1 = A1 + (size_t)((task << 4) + c) * DIM + quad * 8;
    const unsigned short* ap2 = A2 + (size_t)((task << 4) + c) * DIM + quad * 8;
    #pragma unroll
    for (int km = 0; km < 4; ++km){
      a1[km] = *(const short8*)(ap1 + km * 32);
      a2[km] = *(const short8*)(ap2 + km * 32);
    }
  }
  for (; task < ntasks; task += stride){
    int nxt = task + stride;
    int pt = nxt < ntasks ? nxt : task;
    const unsigned short* p1 = A1 + (size_t)((pt << 4) + c) * DIM + quad * 8;
    const unsigned short* p2 = A2 + (size_t)((pt << 4) + c) * DIM + quad * 8;
    short8 n1[4], n2[4];
    #pragma unroll
    for (int km = 0; km < 4; ++km){
      n1[km] = *(const short8*)(p1 + km * 32);
      n2[km] = *(const short8*)(p2 + km * 32);
    }
    floatx4 acc[4];
    #pragma unroll
    for (int j = 0; j < 4; ++j) acc[j] = (floatx4){0.f, 0.f, 0.f, 0.f};
    #pragma unroll
    for (int km = 0; km < 4; ++km){
      #pragma unroll
      for (int j = 0; j < 4; ++j){
        acc[j] = __builtin_amdgcn_mfma_f32_16x16x32_bf16(a1[km], B[0][km][j], acc[j], 0, 0, 0);
        acc[j] = __builtin_amdgcn_mfma_f32_16x16x32_bf16(a2[km], B[1][km][j], acc[j], 0, 0, 0);
      }
    }
    int row0 = task << 4;
    #pragma unroll
    for (int j = 0; j < 4; ++j){
      int colIdx = colbase + j * 16 + c;
      #pragma unroll
      for (int r = 0; r < 4; ++r){
        int row = row0 + quad * 4 + r;
        float v = fmaxf(acc[j][r] + bv[j], 0.f);
        if (OUTBF) outb[(size_t)row * DIM + colIdx] = f2bf(v);
        else       outf[(size_t)row * DIM + colIdx] = v;
      }
    }
    #pragma unroll
    for (int km = 0; km < 4; ++km){ a1[km] = n1[km]; a2[km] = n2[km]; }
  }
}

// ---- fallback LDS GEMM (small-ws path, f32 A2/out) -------------------------

__global__ __launch_bounds__(256) void k_gemm_f(const unsigned short* __restrict__ A1,
    const float* __restrict__ A2f,
    const float* __restrict__ Wl, const float* __restrict__ Wr,
    const float* __restrict__ bias, float* __restrict__ outf, int M)
{
  __shared__ unsigned short lds[2 * 128 * 128];
  for (int h = threadIdx.x; h < 128 * 128; h += 256){
    int k = h >> 7, n = h & 127;
    int idx = n * 128 + ((((k >> 3) ^ (n & 7)) << 3)) + (k & 7);
    lds[idx]         = f2bf(Wl[h]);
    lds[16384 + idx] = f2bf(Wr[h]);
  }
  __syncthreads();
  int lane = threadIdx.x & 63;
  int c = lane & 15, quad = lane >> 4;
  int gwid = blockIdx.x * 4 + (threadIdx.x >> 6);
  int nwaves = gridDim.x * 4;
  int ntasks = M >> 4;
  for (int task = gwid; task < ntasks; task += nwaves){
    int row0 = task << 4;
    floatx4 acc[8];
    #pragma unroll
    for (int j = 0; j < 8; ++j) acc[j] = (floatx4){0.f, 0.f, 0.f, 0.f};
    const unsigned short* ap1 = A1 + (size_t)(row0 + c) * DIM + quad * 8;
    #pragma unroll
    for (int km = 0; km < 4; ++km){
      short8 a = *(const short8*)(ap1 + km * 32);
      int kb = (km << 2) + quad;
      #pragma unroll
      for (int j = 0; j < 8; ++j){
        short8 b = *(const short8*)(&lds[(j * 16 + c) * 128 + ((kb ^ (c & 7)) << 3)]);
        acc[j] = __builtin_amdgcn_mfma_f32_16x16x32_bf16(a, b, acc[j], 0, 0, 0);
      }
    }
    #pragma unroll
    for (int km = 0; km < 4; ++km){
      const float* ap2 = A2f + (size_t)(row0 + c) * DIM + quad * 8;
      float4 p0 = *(const float4*)(ap2 + km * 32);
      float4 p1 = *(const float4*)(ap2 + km * 32 + 4);
      union { short8 v; unsigned short u[8]; } ua;
      ua.u[0] = f2bf(p0.x); ua.u[1] = f2bf(p0.y);
      ua.u[2] = f2bf(p0.z); ua.u[3] = f2bf(p0.w);
      ua.u[4] = f2bf(p1.x); ua.u[5] = f2bf(p1.y);
      ua.u[6] = f2bf(p1.z); ua.u[7] = f2bf(p1.w);
      int kb = (km << 2) + quad;
      #pragma unroll
      for (int j = 0; j < 8; ++j){
        short8 b = *(const short8*)(&lds[16384 + (j * 16 + c) * 128 + ((kb ^ (c & 7)) << 3)]);
        acc[j] = __builtin_amdgcn_mfma_f32_16x16x32_bf16(ua.v, b, acc[j], 0, 0, 0);
      }
    }
    #pragma unroll
    for (int j = 0; j < 8; ++j){
      int colIdx = j * 16 + c;
      float bvv = bias[colIdx];
      #pragma unroll
      for (int r = 0; r < 4; ++r){
        int row = row0 + quad * 4 + r;
        outf[(size_t)row * DIM + colIdx] = fmaxf(acc[j][r] + bvv, 0.f);
      }
    }
  }
}

// ---- host ------------------------------------------------------------------

extern "C" void kernel_launch(void* const* d_in, const int* in_sizes, int n_in,
                              void* d_out, int out_size, void* d_ws, size_t ws_size,
                              hipStream_t stream)
{
  const float* x   = (const float*)d_in[0];
  const int*   ei  = (const int*)d_in[1];
  const float* Wl1 = (const float*)d_in[2];
  const float* bl1 = (const float*)d_in[3];
  const float* Wr1 = (const float*)d_in[4];
  const float* Wl2 = (const float*)d_in[5];
  const float* bl2 = (const float*)d_in[6];
  const float* Wr2 = (const float*)d_in[7];

  const int N = in_sizes[0] / DIM;
  const int E = in_sizes[1] / 2;
  const int* src  = ei;
  const int* dstI = ei + E;
  const int NB = (N + 511) >> 9;   // 196 (must be <= 255 for k_bin's uchar)

  char* p = (char*)d_ws;
  auto alloc = [&](size_t bytes) -> char* {
    char* r = p; p += (bytes + 255) & ~((size_t)255); return r;
  };
  int* rowptr   = (int*)alloc((size_t)(N + 1) * 4);
  int* deg      = (int*)alloc((size_t)N * 4);   // fallback only
  int* bsum     = (int*)alloc(1024);            // fallback only
  int* bktCnt   = (int*)alloc(1024);
  int* bktCur   = (int*)alloc(1024);            // adjacent to bktCnt: one memset
  int* bktBase  = (int*)alloc(2048);            // 257 entries used
  int* col      = (int*)alloc((size_t)E * 4);
  unsigned short* aggb = (unsigned short*)alloc((size_t)N * DIM * 2);
  unsigned short* xb   = (unsigned short*)alloc((size_t)N * DIM * 2);
  unsigned short* h1b  = (unsigned short*)alloc((size_t)N * DIM * 2);
  size_t need_big = (size_t)(p - (char*)d_ws);
  const bool big = (ws_size >= need_big) && (NB <= 255);
  int2* binned = (int2*)aggb;   // overlays aggb (dead until first k_agg write)

  int gE = (E + 255) / 256;
  int gAgg = (N * 64 + 255) / 256;

  if (big){
    int n4 = N * DIM / 4;
    hipMemsetAsync(bktCnt, 0, 2048, stream);   // bktCnt + bktCur
    k_prep<<<1024, 256, 0, stream>>>(x, xb, n4, dstI, E, bktCnt);
    k_scanB<<<1, 256, 0, stream>>>(bktCnt, bktBase, NB);
    k_bin<<<(E + BINCH - 1) / BINCH, 256, 0, stream>>>(src, dstI, E, bktBase, bktCur,
                                                       binned, NB);
    k_csr2<<<NB, 1024, 0, stream>>>(binned, bktBase, N, rowptr, col);
    k_agg_bf<<<gAgg, 256, 0, stream>>>(xb, rowptr, col, aggb, N);
    k_gemm_r<true><<<512, 256, 0, stream>>>(aggb, xb, Wl1, Wr1, bl1,
                                            nullptr, h1b, N);
    k_agg_bf<<<gAgg, 256, 0, stream>>>(h1b, rowptr, col, aggb, N);
    k_gemm_r<false><<<512, 256, 0, stream>>>(aggb, h1b, Wl2, Wr2, bl2,
                                             (float*)d_out, nullptr, N);
  } else {
    hipMemsetAsync(deg, 0, (size_t)N * 4, stream);
    k_hist<<<gE, 256, 0, stream>>>(dstI, E, deg);
    int nb = (N + 1023) / 1024;
    k_scan1<<<nb, 256, 0, stream>>>(deg, N, rowptr, bsum);
    k_scan2<<<1, 128, 0, stream>>>(bsum, nb);
    k_scan3<<<(N + 255) / 256, 256, 0, stream>>>(rowptr, bsum, N, E, /*cursor=*/deg);
    k_fill<<<gE, 256, 0, stream>>>(src, dstI, E, /*cursor=*/deg, col);
    float* h1 = (float*)d_out;
    k_agg_f32<<<gAgg, 256, 0, stream>>>(x, rowptr, col, aggb, N);
    k_gemm_f<<<512, 256, 0, stream>>>(aggb, x, Wl1, Wr1, bl1, h1, N);
    k_agg_f32<<<gAgg, 256, 0, stream>>>(h1, rowptr, col, aggb, N);
    k_gemm_f<<<512, 256, 0, stream>>>(aggb, h1, Wl2, Wr2, bl2, (float*)d_out, N);
  }
}